// Round 4
// baseline (306.587 us; speedup 1.0000x reference)
//
#include <hip/hip_runtime.h>
#include <cstddef>
#include <cstdint>

// Problem constants
constexpr int kB   = 4;
constexpr int kT   = 2048;
constexpr int kD   = 1024;   // d_model
constexpr int kH   = 16;     // heads
constexpr int kDh  = 64;     // head dim
constexpr int kBT  = kB * kT;          // 8192 rows
constexpr int kQKVN = 3 * kD;          // 3072

typedef _Float16 f16x8 __attribute__((ext_vector_type(8)));
typedef _Float16 f16x4 __attribute__((ext_vector_type(4)));
typedef _Float16 f16x2 __attribute__((ext_vector_type(2)));
typedef float    f32x4  __attribute__((ext_vector_type(4)));
typedef float    f32x16 __attribute__((ext_vector_type(16)));

#define GLD16(g, l)                                                        \
    __builtin_amdgcn_global_load_lds(                                      \
        (const __attribute__((address_space(1))) void*)(g),                \
        (__attribute__((address_space(3))) void*)(l), 16, 0, 0)

// raw barrier helpers (T4): never let a barrier drain vmcnt(0); count waits.
#define BAR_LGKM() do {                                                    \
    asm volatile("s_waitcnt lgkmcnt(0)" ::: "memory");                     \
    __builtin_amdgcn_s_barrier();                                          \
} while (0)
#define WAITVM4() asm volatile("s_waitcnt vmcnt(4)" ::: "memory")

static __device__ __forceinline__ int pkrtz_i(float a, float b) {
    auto t = __builtin_amdgcn_cvt_pkrtz(a, b);   // v_cvt_pkrtz_f16_f32
    return *reinterpret_cast<int*>(&t);
}

// ---------------------------------------------------------------------------
// all fp32->fp16 casts + bias concat in one dispatch
// ---------------------------------------------------------------------------
__global__ __launch_bounds__(256) void cast_all(const float* __restrict__ x,
                                                const float* __restrict__ Wq,
                                                const float* __restrict__ Wk,
                                                const float* __restrict__ Wv,
                                                const float* __restrict__ Wo,
                                                const float* __restrict__ bq,
                                                const float* __restrict__ bk,
                                                const float* __restrict__ bv,
                                                _Float16* __restrict__ Xh,
                                                _Float16* __restrict__ Wqkvh,
                                                _Float16* __restrict__ Woh,
                                                float* __restrict__ bqkv) {
    const int i = blockIdx.x * 256 + threadIdx.x;
    if (i >= 3145728) {                 // bias concat: 768 float4 groups
        const int j = i - 3145728;
        if (j < 768) {
            const float* bs = (j < 256) ? bq : (j < 512 ? bk : bv);
            const int jo = j & 255;
            reinterpret_cast<float4*>(bqkv)[j] =
                reinterpret_cast<const float4*>(bs)[jo];
        }
        return;
    }
    const float* src; _Float16* dst; int off;
    if (i < 2097152)      { src = x;  dst = Xh;              off = i; }
    else if (i < 2359296) { src = Wq; dst = Wqkvh;           off = i - 2097152; }
    else if (i < 2621440) { src = Wk; dst = Wqkvh + 1048576; off = i - 2359296; }
    else if (i < 2883584) { src = Wv; dst = Wqkvh + 2097152; off = i - 2621440; }
    else                  { src = Wo; dst = Woh;             off = i - 2883584; }
    const float4 v = reinterpret_cast<const float4*>(src)[off];
    f16x4 o = { (_Float16)v.x, (_Float16)v.y, (_Float16)v.z, (_Float16)v.w };
    reinterpret_cast<f16x4*>(dst)[off] = o;
}

// ---------------------------------------------------------------------------
// fp16 MFMA GEMM (QKV projection): C[M,N] = A[M,K] @ B[N,K]^T + bias
// R13: T3/T4 2-phase double-buffered staging at BK=32 chunk granularity.
//   LDS 2 x (8KB A + 8KB B) = 32 KB (same total as before -> occupancy kept).
//   Per chunk: issue next chunk's GLD16 into buf^1, s_waitcnt vmcnt(4)
//   (counted: current chunk's 4 loads done, next's 4 stay IN FLIGHT across
//   the barrier), s_barrier, compute, lgkmcnt(0), s_barrier.  The compiler's
//   __syncthreads vmcnt(0) drain — the m97-structure ~20% stall — is gone;
//   every staging load now has a full compute phase of latency cover.
// RoPE fused in epilogue for cols<2048; Q half pre-scaled by log2(e)/8.
// ---------------------------------------------------------------------------
__global__ __launch_bounds__(256) void gemm_qkv(const _Float16* __restrict__ A,
                                                const _Float16* __restrict__ B,
                                                const float* __restrict__ bias,
                                                _Float16* __restrict__ C,
                                                int M, int N, int K) {
    constexpr int NCH = 32;               // K=1024 / 32
    __shared__ _Float16 As[2][128 * 32];
    __shared__ _Float16 Bs[2][128 * 32];

    const int tid  = threadIdx.x;
    const int wave = tid >> 6;
    const int lane = tid & 63;
    const int quad = lane >> 4;
    const int r16  = lane & 15;
    const int m0 = blockIdx.x * 128;
    const int n0 = blockIdx.y * 128;

    const int srow = lane >> 2;
    const int scol = (lane & 3) * 8;
    const _Float16* Ag0 = A + (size_t)(m0 + wave * 16 + srow) * K + scol;
    const _Float16* Ag1 = A + (size_t)(m0 + 64 + wave * 16 + srow) * K + scol;
    const _Float16* Bg0 = B + (size_t)(n0 + wave * 16 + srow) * K + scol;
    const _Float16* Bg1 = B + (size_t)(n0 + 64 + wave * 16 + srow) * K + scol;

    const int wm = (wave & 1) * 64;
    const int wn = (wave >> 1) * 64;

    f32x4 acc[4][4] = {};

    // prologue: chunk 0 -> buf 0
    GLD16(Ag0, &As[0][wave * 512]);
    GLD16(Ag1, &As[0][(wave + 4) * 512]);
    GLD16(Bg0, &Bs[0][wave * 512]);
    GLD16(Bg1, &Bs[0][(wave + 4) * 512]);

    #pragma unroll 1
    for (int c = 0; c < NCH; ++c) {
        const int cur = c & 1;
        // issue next chunk (clamped on last iter: dup of chunk 31 into the
        // idle buffer, never consumed -> keeps the vmcnt count uniform)
        const int kn = (c + 1 < NCH ? c + 1 : NCH - 1) * 32;
        GLD16(Ag0 + kn, &As[cur ^ 1][wave * 512]);
        GLD16(Ag1 + kn, &As[cur ^ 1][(wave + 4) * 512]);
        GLD16(Bg0 + kn, &Bs[cur ^ 1][wave * 512]);
        GLD16(Bg1 + kn, &Bs[cur ^ 1][(wave + 4) * 512]);
        WAITVM4();                       // chunk c's 4 loads retired
        __builtin_amdgcn_s_barrier();

        f16x8 a[4], bf[4];
        #pragma unroll
        for (int mi = 0; mi < 4; ++mi)
            a[mi] = *reinterpret_cast<const f16x8*>(
                &As[cur][(wm + mi * 16 + r16) * 32 + quad * 8]);
        #pragma unroll
        for (int ni = 0; ni < 4; ++ni)
            bf[ni] = *reinterpret_cast<const f16x8*>(
                &Bs[cur][(wn + ni * 16 + r16) * 32 + quad * 8]);
        #pragma unroll
        for (int mi = 0; mi < 4; ++mi)
            #pragma unroll
            for (int ni = 0; ni < 4; ++ni)
                acc[mi][ni] = __builtin_amdgcn_mfma_f32_16x16x32_f16(a[mi], bf[ni], acc[mi][ni], 0, 0, 0);

        BAR_LGKM();                      // WAR: my ds_reads done before others' writes
    }

    #pragma unroll
    for (int mi = 0; mi < 4; ++mi) {
        #pragma unroll
        for (int ni = 0; ni < 4; ++ni) {
            const int col = n0 + wn + ni * 16 + r16;
            const float bv = bias[col];
            #pragma unroll
            for (int r = 0; r < 4; ++r) {
                const int row = m0 + wm + mi * 16 + quad * 4 + r;
                float v = acc[mi][ni][r] + bv;
                // pair partner (col^1) lives in lane^1, same (mi,ni,r)
                const float vx = __shfl_xor(v, 1);
                if (col < 2048) {
                    const int t = row & (kT - 1);
                    const int p = (col & 63) >> 1;
                    const float rev = (float)t * ((float)p *
                        (1.0e-4f * 0.15915494309189535f));
                    const float s = __builtin_amdgcn_sinf(rev);
                    const float c = __builtin_amdgcn_cosf(rev);
                    const float sgn = (r16 & 1) ? s : -s;  // even: -s*partner
                    v = v * c + vx * sgn;
                    if (col < 1024) v *= 0.18033688011112443f;  // log2e/8
                }
                C[(size_t)row * N + col] = (_Float16)v;
            }
        }
    }
}

// ---------------------------------------------------------------------------
// Out projection with FUSED split-merge + normalization in the A-staging.
// R13: same 2-phase BK=32 double-buffer as gemm_qkv. A-path staging regs
// are prefetched one chunk ahead; the 16 per-head 1/(l0+l1) values are
// preloaded into a register table (removes in-loop lp loads that would
// otherwise force a fresh vmcnt drain at the merge).
// ---------------------------------------------------------------------------
__global__ __launch_bounds__(256) void gemm_out_fused(
        const _Float16* __restrict__ Op0,
        const _Float16* __restrict__ Op1,
        const float* __restrict__ lp,
        const _Float16* __restrict__ B,
        const float* __restrict__ bias,
        float* __restrict__ C) {
    constexpr int K = 1024, N = 1024, NCH = 32;
    __shared__ _Float16 As2[2][128 * 32];
    __shared__ _Float16 Bs2[2][128 * 32];

    const int tid  = threadIdx.x;
    const int wave = tid >> 6;
    const int lane = tid & 63;
    const int quad = lane >> 4;
    const int r16  = lane & 15;
    const int m0 = blockIdx.x * 128;
    const int n0 = blockIdx.y * 128;

    // B staging (GLD16)
    const int srow = lane >> 2;
    const int scol = (lane & 3) * 8;
    const _Float16* Bg0 = B + (size_t)(n0 + wave * 16 + srow) * K + scol;
    const _Float16* Bg1 = B + (size_t)(n0 + 64 + wave * 16 + srow) * K + scol;

    // A fused staging: thread covers row m0+(tid>>1), 16 cols at (tid&1)*16
    // within each 32-col chunk.
    const int arow = tid >> 1;
    const int half = tid & 1;
    const int row  = m0 + arow;
    const int bb   = row >> 11, tt = row & 2047;
    const size_t abase = (size_t)row * K + half * 16;
    constexpr size_t lstr = (size_t)kB * kH * kT;

    // preload the 16 per-head normalizers (once; removes lp from the loop)
    float linv[16];
    #pragma unroll
    for (int h = 0; h < 16; ++h) {
        const size_t lidx = (size_t)(bb * 16 + h) * 2048 + tt;
        linv[h] = 1.0f / (lp[lidx] + lp[lstr + lidx]);
    }

    const int wm = (wave & 1) * 64;
    const int wn = (wave >> 1) * 64;

    f32x4 acc[4][4] = {};

    // A-merge helper regs: chunk n data = Op0/Op1 at abase + n*32 (+8)
    f16x8 ra0, ra1, rb0, rb1;            // current-to-write chunk regs

    // prologue: regs A(0); issue B(0); regs A(1); write A(0)->As2[0]
    ra0 = *reinterpret_cast<const f16x8*>(Op0 + abase);
    ra1 = *reinterpret_cast<const f16x8*>(Op0 + abase + 8);
    rb0 = *reinterpret_cast<const f16x8*>(Op1 + abase);
    rb1 = *reinterpret_cast<const f16x8*>(Op1 + abase + 8);
    GLD16(Bg0, &Bs2[0][wave * 512]);
    GLD16(Bg1, &Bs2[0][(wave + 4) * 512]);
    f16x8 na0 = *reinterpret_cast<const f16x8*>(Op0 + abase + 32);
    f16x8 na1 = *reinterpret_cast<const f16x8*>(Op0 + abase + 40);
    f16x8 nb0 = *reinterpret_cast<const f16x8*>(Op1 + abase + 32);
    f16x8 nb1 = *reinterpret_cast<const f16x8*>(Op1 + abase + 40);
    {
        const _Float16 lh = (_Float16)linv[0];
        f16x8 s0 = (ra0 + rb0) * lh;
        f16x8 s1 = (ra1 + rb1) * lh;
        *reinterpret_cast<f16x8*>(&As2[0][arow * 32 + half * 16])     = s0;
        *reinterpret_cast<f16x8*>(&As2[0][arow * 32 + half * 16 + 8]) = s1;
    }

    #pragma unroll 1
    for (int c = 0; c < NCH; ++c) {
        const int cur = c & 1;
        const int n1 = (c + 1 < NCH ? c + 1 : NCH - 1);   // chunk to stage
        const int n2 = (c + 2 < NCH ? c + 2 : NCH - 1);   // chunk to prefetch

        // a) merge + ds_write A(n1) from regs loaded last iteration.
        //    (compiler's wait for these regs drains B(c)'s GLD16 too — they
        //    are older in the vm queue — giving B a full phase of cover)
        {
            const _Float16 lh = (_Float16)linv[n1 >> 1];
            f16x8 s0 = (na0 + nb0) * lh;
            f16x8 s1 = (na1 + nb1) * lh;
            *reinterpret_cast<f16x8*>(&As2[cur ^ 1][arow * 32 + half * 16])     = s0;
            *reinterpret_cast<f16x8*>(&As2[cur ^ 1][arow * 32 + half * 16 + 8]) = s1;
        }
        // b) issue B(n1) GLD16 -> buf^1
        GLD16(Bg0 + n1 * 32, &Bs2[cur ^ 1][wave * 512]);
        GLD16(Bg1 + n1 * 32, &Bs2[cur ^ 1][(wave + 4) * 512]);
        // c) prefetch A(n2) regs
        na0 = *reinterpret_cast<const f16x8*>(Op0 + abase + n2 * 32);
        na1 = *reinterpret_cast<const f16x8*>(Op0 + abase + n2 * 32 + 8);
        nb0 = *reinterpret_cast<const f16x8*>(Op1 + abase + n2 * 32);
        nb1 = *reinterpret_cast<const f16x8*>(Op1 + abase + n2 * 32 + 8);
        // d) barrier (ds_writes drained; B(c) already drained at step a)
        BAR_LGKM();

        // e) compute chunk c
        f16x8 a[4], bf[4];
        #pragma unroll
        for (int mi = 0; mi < 4; ++mi)
            a[mi] = *reinterpret_cast<const f16x8*>(
                &As2[cur][(wm + mi * 16 + r16) * 32 + quad * 8]);
        #pragma unroll
        for (int ni = 0; ni < 4; ++ni)
            bf[ni] = *reinterpret_cast<const f16x8*>(
                &Bs2[cur][(wn + ni * 16 + r16) * 32 + quad * 8]);
        #pragma unroll
        for (int mi = 0; mi < 4; ++mi)
            #pragma unroll
            for (int ni = 0; ni < 4; ++ni)
                acc[mi][ni] = __builtin_amdgcn_mfma_f32_16x16x32_f16(a[mi], bf[ni], acc[mi][ni], 0, 0, 0);

        BAR_LGKM();
    }

    #pragma unroll
    for (int mi = 0; mi < 4; ++mi) {
        #pragma unroll
        for (int ni = 0; ni < 4; ++ni) {
            const int col = n0 + wn + ni * 16 + r16;
            const float bv = bias[col];
            #pragma unroll
            for (int r = 0; r < 4; ++r) {
                const int row2 = m0 + wm + mi * 16 + quad * 4 + r;
                C[(size_t)row2 * N + col] = acc[mi][ni][r] + bv;
            }
        }
    }
}

// ---------------------------------------------------------------------------
// V transpose: QKV[,2048+h*64+d] (rows t) -> Vt[bh][d][t'] with the key-slot
// PERMUTATION t' = swap(bit2,bit3 of t within each 16-key group).
// Why: attn's S' C/D layout gives lane (l31,grp) the keys with bit2==grp;
// the PV A-fragment k-index needs bit3==grp. Storing V at the bit2<->bit3
// swapped slot makes every lane's PV A-fragment exactly its own S' registers
// cl*8..cl*8+7 in order -> no cross-lane exchange in attn.
// The permutation is free here (gather-order change only).
// ---------------------------------------------------------------------------
__global__ __launch_bounds__(256) void transpose_v(const _Float16* __restrict__ QKV,
                                                   _Float16* __restrict__ Vt) {
    const int bh = blockIdx.y;
    const int t0 = blockIdx.x * 64;
    const int b = bh >> 4, h = bh & 15;
    __shared__ _Float16 T[64 * 72];

    const int tid = threadIdx.x;
    const int r   = tid >> 2;
    const int c0  = (tid & 3) * 16;
    const _Float16* src = QKV + (size_t)(b * kT + t0 + r) * kQKVN + 2048 + h * 64 + c0;
    *reinterpret_cast<f16x8*>(&T[r * 72 + c0])     = *reinterpret_cast<const f16x8*>(src);
    *reinterpret_cast<f16x8*>(&T[r * 72 + c0 + 8]) = *reinterpret_cast<const f16x8*>(src + 8);
    __syncthreads();

    const int d = tid >> 2, tc0 = (tid & 3) * 16;
    // slot s holds key sigma(s), sigma = swap bits 2<->3 (involution):
    // o0 (slots 0..7)  <- keys {0,1,2,3, 8,9,10,11}
    // o1 (slots 8..15) <- keys {4,5,6,7, 12,13,14,15}
    f16x8 o0, o1;
    #pragma unroll
    for (int j = 0; j < 4; ++j) o0[j]     = T[(tc0 + j)      * 72 + d];
    #pragma unroll
    for (int j = 0; j < 4; ++j) o0[4 + j] = T[(tc0 + 8 + j)  * 72 + d];
    #pragma unroll
    for (int j = 0; j < 4; ++j) o1[j]     = T[(tc0 + 4 + j)  * 72 + d];
    #pragma unroll
    for (int j = 0; j < 4; ++j) o1[4 + j] = T[(tc0 + 12 + j) * 72 + d];
    _Float16* dst = Vt + ((size_t)bh * 64 + d) * kT + t0 + tc0;
    *reinterpret_cast<f16x8*>(dst)     = o0;
    *reinterpret_cast<f16x8*>(dst + 8) = o1;
}

// ---------------------------------------------------------------------------
// Flash attention, split-K (S=2), XCD-locality swizzled 1D grid (1024 blocks):
//   id = qt*8 + (pair&7) + (pair>>3)*64, pair = bh*2+sp -> the 8 q-tile blocks
//   sharing one (bh,sp)'s 256 KB of K/V get IDs congruent mod 8 -> same XCD
//   -> K/V staging re-reads hit that XCD's L2 (R8/R9-verified, FETCH 164->49).
// T3 2-phase KVBLK=64 double-buffer, one barrier per tile, raw lgkm barriers;
// ds_writes to buf^1 at phase top, global prefetch loads stay in flight
// across barriers (R12-verified: 93.7 -> 91.8 us).
// Max-free softmax => splits merge LINEARLY (O = sum O_s, l = sum l_s);
// merge happens inside gemm_out_fused.
// V slot-permuted in Vt -> PV A-frag is lane-local (no exchange).
// C/D layout: col = lane&31, row = (reg&3) + 8*(reg>>2) + 4*(lane>>5).
// A/B frag: row/col = lane&31, k = (lane>>5)*8 + j.  [HW-verified R3-R9]
// ---------------------------------------------------------------------------
__global__ __launch_bounds__(256) void attn_mfma(const _Float16* __restrict__ QKV,
                                                 const _Float16* __restrict__ Vt,
                                                 _Float16* __restrict__ Op0,
                                                 _Float16* __restrict__ Op1,
                                                 float* __restrict__ lp) {
    constexpr int LDK = 72, LDV = 72;
    __shared__ _Float16 Ks[2][64 * LDK];   // [buf][key 0..64)[d 0..64)
    __shared__ _Float16 Vts[2][64 * LDV];  // [buf][d 0..64)[slot 0..64)

    // swizzled decode
    const int id   = blockIdx.x;              // 0..1023
    const int qt   = (id >> 3) & 7;
    const int pair = ((id >> 6) << 3) + (id & 7);   // 0..127
    const int bh = pair >> 1;
    const int sp = pair & 1;
    const int b = bh >> 4, h = bh & 15;
    const int q0 = qt * 256;

    _Float16* __restrict__ Opart = sp ? Op1 : Op0;
    float* __restrict__ lpart = lp + (size_t)sp * (kB * kH * kT);

    const int tid  = threadIdx.x;
    const int wave = tid >> 6;
    const int lane = tid & 63;
    const int l31  = lane & 31;
    const int grp  = lane >> 5;
    const int qw   = wave * 64;

    // Q B-fragments from global (rope + log2e/8 scale already applied)
    f16x8 aq[2][4];
    #pragma unroll
    for (int qg = 0; qg < 2; ++qg) {
        const _Float16* qrow = QKV + (size_t)(b * kT + q0 + qw + qg * 32 + l31) * kQKVN + h * 64 + grp * 8;
        #pragma unroll
        for (int c = 0; c < 4; ++c)
            aq[qg][c] = *reinterpret_cast<const f16x8*>(qrow + c * 16);
    }

    f32x16 Oacc[2][2] = {};
    float lsum[2] = { 0.f, 0.f };

    // staging mapping: thread t covers row t>>2 (K: key; V: d), 16 f16 at (t&3)*16
    const int sr = tid >> 2;
    const int sc = (tid & 3) * 16;
    const int sofs = sr * LDK + sc;              // LDK == LDV
    const _Float16* kg = QKV + (size_t)(b * kT + sp * 1024 + sr) * kQKVN + 1024 + h * 64 + sc;
    const _Float16* vg = Vt + ((size_t)bh * 64 + sr) * (size_t)kT + sp * 1024 + sc;

    f16x8 kb0, kb1, vb0, vb1;

    // prologue: tile 0 -> regs -> buf0
    kb0 = *reinterpret_cast<const f16x8*>(kg);
    kb1 = *reinterpret_cast<const f16x8*>(kg + 8);
    vb0 = *reinterpret_cast<const f16x8*>(vg);
    vb1 = *reinterpret_cast<const f16x8*>(vg + 8);
    kg += (size_t)64 * kQKVN;  vg += 64;
    *reinterpret_cast<f16x8*>(&Ks[0][sofs])      = kb0;
    *reinterpret_cast<f16x8*>(&Ks[0][sofs + 8])  = kb1;
    *reinterpret_cast<f16x8*>(&Vts[0][sofs])     = vb0;
    *reinterpret_cast<f16x8*>(&Vts[0][sofs + 8]) = vb1;
    // tile 1 -> regs (loads stay in flight across the barrier)
    kb0 = *reinterpret_cast<const f16x8*>(kg);
    kb1 = *reinterpret_cast<const f16x8*>(kg + 8);
    vb0 = *reinterpret_cast<const f16x8*>(vg);
    vb1 = *reinterpret_cast<const f16x8*>(vg + 8);
    kg += (size_t)64 * kQKVN;  vg += 64;
    BAR_LGKM();

    #pragma unroll 1
    for (int it = 0; it < 16; ++it) {
        const int cur = it & 1;

        // phase top: write tile it+1 into buf^1 (overlaps compute on buf[cur])
        if (it < 15) {
            _Float16* kd = &Ks[cur ^ 1][sofs];
            _Float16* vd = &Vts[cur ^ 1][sofs];
            *reinterpret_cast<f16x8*>(kd)     = kb0;
            *reinterpret_cast<f16x8*>(kd + 8) = kb1;
            *reinterpret_cast<f16x8*>(vd)     = vb0;
            *reinterpret_cast<f16x8*>(vd + 8) = vb1;
        }
        // issue tile it+2's global loads (drained only by next phase's writes)
        if (it < 14) {
            kb0 = *reinterpret_cast<const f16x8*>(kg);
            kb1 = *reinterpret_cast<const f16x8*>(kg + 8);
            vb0 = *reinterpret_cast<const f16x8*>(vg);
            vb1 = *reinterpret_cast<const f16x8*>(vg + 8);
            kg += (size_t)64 * kQKVN;  vg += 64;
        }

        const _Float16* Kb = &Ks[cur][0];
        const _Float16* Vb = &Vts[cur][0];

        #pragma unroll
        for (int kt = 0; kt < 2; ++kt) {
            f16x8 kf[4];
            #pragma unroll
            for (int c = 0; c < 4; ++c)
                kf[c] = *reinterpret_cast<const f16x8*>(&Kb[(kt * 32 + l31) * LDK + c * 16 + grp * 8]);

            f16x8 pfrag[2][2];
            #pragma unroll
            for (int qg = 0; qg < 2; ++qg) {
                f32x16 S = {};
                __builtin_amdgcn_s_setprio(1);
                #pragma unroll
                for (int c = 0; c < 4; ++c)
                    S = __builtin_amdgcn_mfma_f32_32x32x16_f16(kf[c], aq[qg][c], S, 0, 0, 0);
                __builtin_amdgcn_s_setprio(0);

                int q32[4][2];
                #pragma unroll
                for (int g = 0; g < 4; ++g) {
                    const float e0 = __builtin_amdgcn_exp2f(S[g * 4 + 0]);
                    const float e1 = __builtin_amdgcn_exp2f(S[g * 4 + 1]);
                    const float e2 = __builtin_amdgcn_exp2f(S[g * 4 + 2]);
                    const float e3 = __builtin_amdgcn_exp2f(S[g * 4 + 3]);
                    lsum[qg] += (e0 + e1) + (e2 + e3);
                    q32[g][0] = pkrtz_i(e0, e1);
                    q32[g][1] = pkrtz_i(e2, e3);
                }
                // V slot-permutation makes the PV A-frag lane-local:
                // pfrag[cl] = e[cl*8 + 0..7] packed, no exchange.
                #pragma unroll
                for (int cl = 0; cl < 2; ++cl) {
                    union { int u[4]; f16x8 v; } pu;
                    pu.u[0] = q32[2 * cl][0];
                    pu.u[1] = q32[2 * cl][1];
                    pu.u[2] = q32[2 * cl + 1][0];
                    pu.u[3] = q32[2 * cl + 1][1];
                    pfrag[qg][cl] = pu.v;
                }
            }

            __builtin_amdgcn_s_setprio(1);
            #pragma unroll
            for (int cl = 0; cl < 2; ++cl) {
                #pragma unroll
                for (int nt = 0; nt < 2; ++nt) {
                    f16x8 vf = *reinterpret_cast<const f16x8*>(
                        &Vb[(nt * 32 + l31) * LDV + kt * 32 + cl * 16 + grp * 8]);
                    Oacc[0][nt] = __builtin_amdgcn_mfma_f32_32x32x16_f16(pfrag[0][cl], vf, Oacc[0][nt], 0, 0, 0);
                    Oacc[1][nt] = __builtin_amdgcn_mfma_f32_32x32x16_f16(pfrag[1][cl], vf, Oacc[1][nt], 0, 0, 0);
                }
            }
            __builtin_amdgcn_s_setprio(0);
        }

        BAR_LGKM();
    }

    // l partials
    lsum[0] += __shfl_xor(lsum[0], 32);
    lsum[1] += __shfl_xor(lsum[1], 32);
    if (grp == 0) {
        lpart[(size_t)bh * kT + q0 + qw + l31]      = lsum[0];
        lpart[(size_t)bh * kT + q0 + qw + 32 + l31] = lsum[1];
    }

    // unnormalized partial O (fp16)
    #pragma unroll
    for (int qg = 0; qg < 2; ++qg)
        #pragma unroll
        for (int g = 0; g < 4; ++g)
            #pragma unroll
            for (int r = 0; r < 4; ++r) {
                const int reg = g * 4 + r;
                const int ql  = r + 8 * g + 4 * grp;
                const size_t orow = (size_t)(b * kT + q0 + qw + qg * 32 + ql);
                #pragma unroll
                for (int nt = 0; nt < 2; ++nt)
                    Opart[orow * kD + h * 64 + nt * 32 + l31] = (_Float16)Oacc[qg][nt][reg];
            }
}

// ---------------------------------------------------------------------------
extern "C" void kernel_launch(void* const* d_in, const int* in_sizes, int n_in,
                              void* d_out, int out_size, void* d_ws, size_t ws_size,
                              hipStream_t stream) {
    const float* x  = (const float*)d_in[0];
    const float* Wq = (const float*)d_in[1];
    const float* bq = (const float*)d_in[2];
    const float* Wk = (const float*)d_in[3];
    const float* bk = (const float*)d_in[4];
    const float* Wv = (const float*)d_in[5];
    const float* bv = (const float*)d_in[6];
    const float* Wo = (const float*)d_in[7];
    const float* bo = (const float*)d_in[8];
    float* out = (float*)d_out;

    char* ws = (char*)d_ws;
    _Float16* Xh    = (_Float16*)(ws);                         // 16 MB (-> Op0)
    _Float16* Wqkvh = (_Float16*)(ws + 16777216);              // 6 MB (-> lp[2])
    _Float16* Woh   = (_Float16*)(ws + 23068672);              // 2 MB
    float*    bqkv  = (float*)   (ws + 25165824);              // 16 KB
    _Float16* QKVh  = (_Float16*)(ws + 25182208);              // 48 MB
    _Float16* Vtb   = (_Float16*)(ws + 75513856);              // 16 MB
    _Float16* Ohb   = (_Float16*)(ws + 92291072);              // 16 MB (-> Op1)

    _Float16* Op0 = Xh;                        // dead after QKV GEMM
    _Float16* Op1 = Ohb;
    float*    lp  = (float*)(ws + 16777216);   // 2 x 512 KB in dead Wqkvh

    // casts + bias concat
    cast_all<<<12291, 256, 0, stream>>>(x, Wq, Wk, Wv, Wo, bq, bk, bv,
                                        Xh, Wqkvh, Woh, bqkv);

    // fused QKV projection with RoPE epilogue (2-phase counted-vmcnt)
    gemm_qkv<<<dim3(kBT / 128, kQKVN / 128), 256, 0, stream>>>(
        Xh, Wqkvh, bqkv, QKVh, kBT, kQKVN, kD);

    // V -> Vt[bh][d][t] (key-slot permuted)
    transpose_v<<<dim3(kT / 64, kB * kH), 256, 0, stream>>>(QKVh, Vtb);

    // split-K flash attention (S=2), 2-phase double-buffered, raw barriers
    attn_mfma<<<1024, 256, 0, stream>>>(QKVh, Vtb, Op0, Op1, lp);

    // output projection with fused split-merge + normalization (2-phase)
    gemm_out_fused<<<dim3(kBT / 128, kD / 128), 256, 0, stream>>>(
        Op0, Op1, lp, Woh, bo, out);
}

// Round 5
// 305.370 us; speedup vs baseline: 1.0040x; 1.0040x over previous
//
#include <hip/hip_runtime.h>
#include <cstddef>
#include <cstdint>

// Problem constants
constexpr int kB   = 4;
constexpr int kT   = 2048;
constexpr int kD   = 1024;   // d_model
constexpr int kH   = 16;     // heads
constexpr int kDh  = 64;     // head dim
constexpr int kBT  = kB * kT;          // 8192 rows
constexpr int kQKVN = 3 * kD;          // 3072

typedef _Float16 f16x8 __attribute__((ext_vector_type(8)));
typedef _Float16 f16x4 __attribute__((ext_vector_type(4)));
typedef _Float16 f16x2 __attribute__((ext_vector_type(2)));
typedef float    f32x4  __attribute__((ext_vector_type(4)));
typedef float    f32x16 __attribute__((ext_vector_type(16)));

#define GLD16(g, l)                                                        \
    __builtin_amdgcn_global_load_lds(                                      \
        (const __attribute__((address_space(1))) void*)(g),                \
        (__attribute__((address_space(3))) void*)(l), 16, 0, 0)

// raw barrier: drain LDS ops only, leave global prefetch loads in flight
#define BAR_LGKM() do {                                                    \
    asm volatile("s_waitcnt lgkmcnt(0)" ::: "memory");                     \
    __builtin_amdgcn_s_barrier();                                          \
} while (0)

static __device__ __forceinline__ int pkrtz_i(float a, float b) {
    auto t = __builtin_amdgcn_cvt_pkrtz(a, b);   // v_cvt_pkrtz_f16_f32
    return *reinterpret_cast<int*>(&t);
}

// ---------------------------------------------------------------------------
// all fp32->fp16 casts + bias concat in one dispatch
// ---------------------------------------------------------------------------
__global__ __launch_bounds__(256) void cast_all(const float* __restrict__ x,
                                                const float* __restrict__ Wq,
                                                const float* __restrict__ Wk,
                                                const float* __restrict__ Wv,
                                                const float* __restrict__ Wo,
                                                const float* __restrict__ bq,
                                                const float* __restrict__ bk,
                                                const float* __restrict__ bv,
                                                _Float16* __restrict__ Xh,
                                                _Float16* __restrict__ Wqkvh,
                                                _Float16* __restrict__ Woh,
                                                float* __restrict__ bqkv) {
    const int i = blockIdx.x * 256 + threadIdx.x;
    if (i >= 3145728) {                 // bias concat: 768 float4 groups
        const int j = i - 3145728;
        if (j < 768) {
            const float* bs = (j < 256) ? bq : (j < 512 ? bk : bv);
            const int jo = j & 255;
            reinterpret_cast<float4*>(bqkv)[j] =
                reinterpret_cast<const float4*>(bs)[jo];
        }
        return;
    }
    const float* src; _Float16* dst; int off;
    if (i < 2097152)      { src = x;  dst = Xh;              off = i; }
    else if (i < 2359296) { src = Wq; dst = Wqkvh;           off = i - 2097152; }
    else if (i < 2621440) { src = Wk; dst = Wqkvh + 1048576; off = i - 2359296; }
    else if (i < 2883584) { src = Wv; dst = Wqkvh + 2097152; off = i - 2621440; }
    else                  { src = Wo; dst = Woh;             off = i - 2883584; }
    const float4 v = reinterpret_cast<const float4*>(src)[off];
    f16x4 o = { (_Float16)v.x, (_Float16)v.y, (_Float16)v.z, (_Float16)v.w };
    reinterpret_cast<f16x4*>(dst)[off] = o;
}

// ---------------------------------------------------------------------------
// fp16 MFMA GEMM (QKV projection): C[M,N] = A[M,K] @ B[N,K]^T + bias
// BK=64 staged as two 32-K chunks in separate LDS regions (GLD16-compatible).
// 2D grid (default dispatch order). R14: V-tiles (n0>=2048, block-uniform)
// write DIRECTLY into Vt[bh][d][t'] with the key-slot permutation
// (t' = swap bits 2<->3 of t within each 16-group; for reg quad q this is
// just quad' = swap(q1<->q2)), one f16x4 8B store per (mi,ni) — the
// transpose_v dispatch is eliminated and V is never written to QKVh.
// RoPE fused in the epilogue for cols<2048 (pair partner is lane^1); Q half
// pre-scaled by log2(e)/8 for the max-free exp2 softmax.
// ---------------------------------------------------------------------------
__global__ __launch_bounds__(256) void gemm_qkv(const _Float16* __restrict__ A,
                                                const _Float16* __restrict__ B,
                                                const float* __restrict__ bias,
                                                _Float16* __restrict__ C,
                                                _Float16* __restrict__ Vt,
                                                int M, int N, int K) {
    constexpr int BK = 64;
    __shared__ _Float16 As[128 * BK];   // [ko][128][32] chunked
    __shared__ _Float16 Bs[128 * BK];

    const int tid  = threadIdx.x;
    const int wave = tid >> 6;
    const int lane = tid & 63;
    const int quad = lane >> 4;
    const int r16  = lane & 15;
    const int m0 = blockIdx.x * 128;
    const int n0 = blockIdx.y * 128;

    const int srow = lane >> 2;
    const int scol = (lane & 3) * 8;
    const _Float16* Ag0 = A + (size_t)(m0 + wave * 16 + srow) * K + scol;
    const _Float16* Ag1 = A + (size_t)(m0 + 64 + wave * 16 + srow) * K + scol;
    const _Float16* Bg0 = B + (size_t)(n0 + wave * 16 + srow) * K + scol;
    const _Float16* Bg1 = B + (size_t)(n0 + 64 + wave * 16 + srow) * K + scol;
    _Float16* Al0 = &As[(size_t)wave * 512];
    _Float16* Al1 = &As[(size_t)(wave + 4) * 512];
    _Float16* Bl0 = &Bs[(size_t)wave * 512];
    _Float16* Bl1 = &Bs[(size_t)(wave + 4) * 512];

    const int wm = (wave & 1) * 64;
    const int wn = (wave >> 1) * 64;

    f32x4 acc[4][4] = {};

    for (int k0 = 0; k0 < K; k0 += BK) {
        GLD16(Ag0 + k0,      Al0);
        GLD16(Ag1 + k0,      Al1);
        GLD16(Ag0 + k0 + 32, Al0 + 4096);
        GLD16(Ag1 + k0 + 32, Al1 + 4096);
        GLD16(Bg0 + k0,      Bl0);
        GLD16(Bg1 + k0,      Bl1);
        GLD16(Bg0 + k0 + 32, Bl0 + 4096);
        GLD16(Bg1 + k0 + 32, Bl1 + 4096);
        __syncthreads();

        #pragma unroll
        for (int ko = 0; ko < 2; ++ko) {
            f16x8 a[4], bf[4];
            #pragma unroll
            for (int mi = 0; mi < 4; ++mi)
                a[mi] = *reinterpret_cast<const f16x8*>(
                    &As[ko * 4096 + (wm + mi * 16 + r16) * 32 + quad * 8]);
            #pragma unroll
            for (int ni = 0; ni < 4; ++ni)
                bf[ni] = *reinterpret_cast<const f16x8*>(
                    &Bs[ko * 4096 + (wn + ni * 16 + r16) * 32 + quad * 8]);
            #pragma unroll
            for (int mi = 0; mi < 4; ++mi)
                #pragma unroll
                for (int ni = 0; ni < 4; ++ni)
                    acc[mi][ni] = __builtin_amdgcn_mfma_f32_16x16x32_f16(a[mi], bf[ni], acc[mi][ni], 0, 0, 0);
        }
        __syncthreads();
    }

    if (n0 < 2048) {
        // Q/K epilogue: RoPE + (Q) log2e/8 scale, write to QKV buffer
        #pragma unroll
        for (int mi = 0; mi < 4; ++mi) {
            #pragma unroll
            for (int ni = 0; ni < 4; ++ni) {
                const int col = n0 + wn + ni * 16 + r16;
                const float bv = bias[col];
                #pragma unroll
                for (int r = 0; r < 4; ++r) {
                    const int row = m0 + wm + mi * 16 + quad * 4 + r;
                    float v = acc[mi][ni][r] + bv;
                    // pair partner (col^1) lives in lane^1, same (mi,ni,r)
                    const float vx = __shfl_xor(v, 1);
                    const int t = row & (kT - 1);
                    const int p = (col & 63) >> 1;
                    const float rev = (float)t * ((float)p *
                        (1.0e-4f * 0.15915494309189535f));
                    const float s = __builtin_amdgcn_sinf(rev);
                    const float c = __builtin_amdgcn_cosf(rev);
                    const float sgn = (r16 & 1) ? s : -s;  // even: -s*partner
                    v = v * c + vx * sgn;
                    if (col < 1024) v *= 0.18033688011112443f;  // log2e/8
                    C[(size_t)row * N + col] = (_Float16)v;
                }
            }
        }
    } else {
        // V epilogue: write transposed + slot-permuted into Vt[bh][d][t'].
        // reg r of quad q = key offset q*4+r -> slot quad2*4+r,
        // quad2 = swap(q bit0 <-> bit1). 4 r-values contiguous -> f16x4.
        const int quad2 = ((quad & 1) << 1) | (quad >> 1);
        const int b2 = (m0 + wm) >> 11;                 // block never straddles b
        const int tb = ((m0 + wm) & (kT - 1)) + quad2 * 4;
        #pragma unroll
        for (int mi = 0; mi < 4; ++mi) {
            #pragma unroll
            for (int ni = 0; ni < 4; ++ni) {
                const int col = n0 + wn + ni * 16 + r16;
                const float bv = bias[col];
                const int vd = col - 2048;
                const int h = vd >> 6, d = vd & 63;
                f16x4 o;
                #pragma unroll
                for (int r = 0; r < 4; ++r)
                    o[r] = (_Float16)(acc[mi][ni][r] + bv);
                _Float16* dst = Vt + ((size_t)(b2 * 16 + h) * 64 + d) * kT
                                + tb + mi * 16;
                *reinterpret_cast<f16x4*>(dst) = o;
            }
        }
    }
}

// ---------------------------------------------------------------------------
// Out projection with FUSED split-merge + normalization in the A-staging:
// A_norm[row][k] = (Op0[row][k] + Op1[row][k]) / (l0[row,h] + l1[row,h]),
// h = k>>6 (each thread's 32-col staging chunk lies within one head).
// B staged via GLD16 as usual. C written fp32.  (R2 structure, verified.)
// ---------------------------------------------------------------------------
__global__ __launch_bounds__(256) void gemm_out_fused(
        const _Float16* __restrict__ Op0,
        const _Float16* __restrict__ Op1,
        const float* __restrict__ lp,
        const _Float16* __restrict__ B,
        const float* __restrict__ bias,
        float* __restrict__ C) {
    constexpr int K = 1024, N = 1024, BK = 64;
    __shared__ _Float16 As[128 * BK];   // [ko][128][32] chunked
    __shared__ _Float16 Bs[128 * BK];

    const int tid  = threadIdx.x;
    const int wave = tid >> 6;
    const int lane = tid & 63;
    const int quad = lane >> 4;
    const int r16  = lane & 15;
    const int m0 = blockIdx.x * 128;
    const int n0 = blockIdx.y * 128;

    // B staging (GLD16)
    const int srow = lane >> 2;
    const int scol = (lane & 3) * 8;
    const _Float16* Bg0 = B + (size_t)(n0 + wave * 16 + srow) * K + scol;
    const _Float16* Bg1 = B + (size_t)(n0 + 64 + wave * 16 + srow) * K + scol;
    _Float16* Bl0 = &Bs[(size_t)wave * 512];
    _Float16* Bl1 = &Bs[(size_t)(wave + 4) * 512];

    // A fused staging: thread covers row m0+(tid>>1), 32 cols at (tid&1)*32
    const int arow = tid >> 1;
    const int ko_s = tid & 1;
    const int row  = m0 + arow;
    const int bb   = row >> 11, tt = row & 2047;
    const size_t abase = (size_t)row * K + ko_s * 32;
    constexpr size_t lstr = (size_t)kB * kH * kT;

    const int wm = (wave & 1) * 64;
    const int wn = (wave >> 1) * 64;

    f32x4 acc[4][4] = {};

    for (int k0 = 0; k0 < K; k0 += BK) {
        GLD16(Bg0 + k0,      Bl0);
        GLD16(Bg1 + k0,      Bl1);
        GLD16(Bg0 + k0 + 32, Bl0 + 4096);
        GLD16(Bg1 + k0 + 32, Bl1 + 4096);

        // A: load partials, merge + normalize, write LDS
        {
            const int h = k0 >> 6;   // iter-uniform head
            const size_t lidx = (size_t)(bb * 16 + h) * 2048 + tt;
            const float linv = 1.0f / (lp[lidx] + lp[lstr + lidx]);
            const _Float16 lh = (_Float16)linv;
            #pragma unroll
            for (int j = 0; j < 4; ++j) {
                f16x8 a0 = *reinterpret_cast<const f16x8*>(Op0 + abase + k0 + 8 * j);
                f16x8 a1 = *reinterpret_cast<const f16x8*>(Op1 + abase + k0 + 8 * j);
                f16x8 s = (a0 + a1) * lh;     // v_pk_add_f16 / v_pk_mul_f16
                *reinterpret_cast<f16x8*>(&As[ko_s * 4096 + arow * 32 + 8 * j]) = s;
            }
        }
        __syncthreads();

        #pragma unroll
        for (int ko = 0; ko < 2; ++ko) {
            f16x8 a[4], bf[4];
            #pragma unroll
            for (int mi = 0; mi < 4; ++mi)
                a[mi] = *reinterpret_cast<const f16x8*>(
                    &As[ko * 4096 + (wm + mi * 16 + r16) * 32 + quad * 8]);
            #pragma unroll
            for (int ni = 0; ni < 4; ++ni)
                bf[ni] = *reinterpret_cast<const f16x8*>(
                    &Bs[ko * 4096 + (wn + ni * 16 + r16) * 32 + quad * 8]);
            #pragma unroll
            for (int mi = 0; mi < 4; ++mi)
                #pragma unroll
                for (int ni = 0; ni < 4; ++ni)
                    acc[mi][ni] = __builtin_amdgcn_mfma_f32_16x16x32_f16(a[mi], bf[ni], acc[mi][ni], 0, 0, 0);
        }
        __syncthreads();
    }

    #pragma unroll
    for (int mi = 0; mi < 4; ++mi) {
        #pragma unroll
        for (int ni = 0; ni < 4; ++ni) {
            const int col = n0 + wn + ni * 16 + r16;
            const float bv = bias[col];
            #pragma unroll
            for (int r = 0; r < 4; ++r) {
                const int row2 = m0 + wm + mi * 16 + quad * 4 + r;
                C[(size_t)row2 * N + col] = acc[mi][ni][r] + bv;
            }
        }
    }
}

// ---------------------------------------------------------------------------
// Flash attention, split-K (S=2), XCD-locality swizzled 1D grid (1024 blocks):
//   id = qt*8 + (pair&7) + (pair>>3)*64, pair = bh*2+sp -> the 8 q-tile blocks
//   sharing one (bh,sp)'s 256 KB of K/V get IDs congruent mod 8 -> same XCD
//   -> K/V staging re-reads hit that XCD's L2 (R8/R9-verified, FETCH 164->49).
// T3 2-phase KVBLK=64 double-buffer, one barrier per tile, raw lgkm barriers;
// ds_writes to buf^1 at phase top, global prefetch loads stay in flight
// across barriers (R12-verified: 93.7 -> 91.8 us).
// Max-free softmax => splits merge LINEARLY (O = sum O_s, l = sum l_s);
// merge happens inside gemm_out_fused.
// V slot-permuted in Vt -> PV A-frag is lane-local (no exchange).
// C/D layout: col = lane&31, row = (reg&3) + 8*(reg>>2) + 4*(lane>>5).
// A/B frag: row/col = lane&31, k = (lane>>5)*8 + j.  [HW-verified R3-R9]
// ---------------------------------------------------------------------------
__global__ __launch_bounds__(256) void attn_mfma(const _Float16* __restrict__ QKV,
                                                 const _Float16* __restrict__ Vt,
                                                 _Float16* __restrict__ Op0,
                                                 _Float16* __restrict__ Op1,
                                                 float* __restrict__ lp) {
    constexpr int LDK = 72, LDV = 72;
    __shared__ _Float16 Ks[2][64 * LDK];   // [buf][key 0..64)[d 0..64)
    __shared__ _Float16 Vts[2][64 * LDV];  // [buf][d 0..64)[slot 0..64)

    // swizzled decode
    const int id   = blockIdx.x;              // 0..1023
    const int qt   = (id >> 3) & 7;
    const int pair = ((id >> 6) << 3) + (id & 7);   // 0..127
    const int bh = pair >> 1;
    const int sp = pair & 1;
    const int b = bh >> 4, h = bh & 15;
    const int q0 = qt * 256;

    _Float16* __restrict__ Opart = sp ? Op1 : Op0;
    float* __restrict__ lpart = lp + (size_t)sp * (kB * kH * kT);

    const int tid  = threadIdx.x;
    const int wave = tid >> 6;
    const int lane = tid & 63;
    const int l31  = lane & 31;
    const int grp  = lane >> 5;
    const int qw   = wave * 64;

    // Q B-fragments from global (rope + log2e/8 scale already applied)
    f16x8 aq[2][4];
    #pragma unroll
    for (int qg = 0; qg < 2; ++qg) {
        const _Float16* qrow = QKV + (size_t)(b * kT + q0 + qw + qg * 32 + l31) * kQKVN + h * 64 + grp * 8;
        #pragma unroll
        for (int c = 0; c < 4; ++c)
            aq[qg][c] = *reinterpret_cast<const f16x8*>(qrow + c * 16);
    }

    f32x16 Oacc[2][2] = {};
    float lsum[2] = { 0.f, 0.f };

    // staging mapping: thread t covers row t>>2 (K: key; V: d), 16 f16 at (t&3)*16
    const int sr = tid >> 2;
    const int sc = (tid & 3) * 16;
    const int sofs = sr * LDK + sc;              // LDK == LDV
    const _Float16* kg = QKV + (size_t)(b * kT + sp * 1024 + sr) * kQKVN + 1024 + h * 64 + sc;
    const _Float16* vg = Vt + ((size_t)bh * 64 + sr) * (size_t)kT + sp * 1024 + sc;

    f16x8 kb0, kb1, vb0, vb1;

    // prologue: tile 0 -> regs -> buf0
    kb0 = *reinterpret_cast<const f16x8*>(kg);
    kb1 = *reinterpret_cast<const f16x8*>(kg + 8);
    vb0 = *reinterpret_cast<const f16x8*>(vg);
    vb1 = *reinterpret_cast<const f16x8*>(vg + 8);
    kg += (size_t)64 * kQKVN;  vg += 64;
    *reinterpret_cast<f16x8*>(&Ks[0][sofs])      = kb0;
    *reinterpret_cast<f16x8*>(&Ks[0][sofs + 8])  = kb1;
    *reinterpret_cast<f16x8*>(&Vts[0][sofs])     = vb0;
    *reinterpret_cast<f16x8*>(&Vts[0][sofs + 8]) = vb1;
    // tile 1 -> regs (loads stay in flight across the barrier)
    kb0 = *reinterpret_cast<const f16x8*>(kg);
    kb1 = *reinterpret_cast<const f16x8*>(kg + 8);
    vb0 = *reinterpret_cast<const f16x8*>(vg);
    vb1 = *reinterpret_cast<const f16x8*>(vg + 8);
    kg += (size_t)64 * kQKVN;  vg += 64;
    BAR_LGKM();

    #pragma unroll 1
    for (int it = 0; it < 16; ++it) {
        const int cur = it & 1;

        // phase top: write tile it+1 into buf^1 (overlaps compute on buf[cur])
        if (it < 15) {
            _Float16* kd = &Ks[cur ^ 1][sofs];
            _Float16* vd = &Vts[cur ^ 1][sofs];
            *reinterpret_cast<f16x8*>(kd)     = kb0;
            *reinterpret_cast<f16x8*>(kd + 8) = kb1;
            *reinterpret_cast<f16x8*>(vd)     = vb0;
            *reinterpret_cast<f16x8*>(vd + 8) = vb1;
        }
        // issue tile it+2's global loads (drained only by next phase's writes)
        if (it < 14) {
            kb0 = *reinterpret_cast<const f16x8*>(kg);
            kb1 = *reinterpret_cast<const f16x8*>(kg + 8);
            vb0 = *reinterpret_cast<const f16x8*>(vg);
            vb1 = *reinterpret_cast<const f16x8*>(vg + 8);
            kg += (size_t)64 * kQKVN;  vg += 64;
        }

        const _Float16* Kb = &Ks[cur][0];
        const _Float16* Vb = &Vts[cur][0];

        #pragma unroll
        for (int kt = 0; kt < 2; ++kt) {
            f16x8 kf[4];
            #pragma unroll
            for (int c = 0; c < 4; ++c)
                kf[c] = *reinterpret_cast<const f16x8*>(&Kb[(kt * 32 + l31) * LDK + c * 16 + grp * 8]);

            f16x8 pfrag[2][2];
            #pragma unroll
            for (int qg = 0; qg < 2; ++qg) {
                f32x16 S = {};
                __builtin_amdgcn_s_setprio(1);
                #pragma unroll
                for (int c = 0; c < 4; ++c)
                    S = __builtin_amdgcn_mfma_f32_32x32x16_f16(kf[c], aq[qg][c], S, 0, 0, 0);
                __builtin_amdgcn_s_setprio(0);

                int q32[4][2];
                #pragma unroll
                for (int g = 0; g < 4; ++g) {
                    const float e0 = __builtin_amdgcn_exp2f(S[g * 4 + 0]);
                    const float e1 = __builtin_amdgcn_exp2f(S[g * 4 + 1]);
                    const float e2 = __builtin_amdgcn_exp2f(S[g * 4 + 2]);
                    const float e3 = __builtin_amdgcn_exp2f(S[g * 4 + 3]);
                    lsum[qg] += (e0 + e1) + (e2 + e3);
                    q32[g][0] = pkrtz_i(e0, e1);
                    q32[g][1] = pkrtz_i(e2, e3);
                }
                // V slot-permutation makes the PV A-frag lane-local:
                // pfrag[cl] = e[cl*8 + 0..7] packed, no exchange.
                #pragma unroll
                for (int cl = 0; cl < 2; ++cl) {
                    union { int u[4]; f16x8 v; } pu;
                    pu.u[0] = q32[2 * cl][0];
                    pu.u[1] = q32[2 * cl][1];
                    pu.u[2] = q32[2 * cl + 1][0];
                    pu.u[3] = q32[2 * cl + 1][1];
                    pfrag[qg][cl] = pu.v;
                }
            }

            __builtin_amdgcn_s_setprio(1);
            #pragma unroll
            for (int cl = 0; cl < 2; ++cl) {
                #pragma unroll
                for (int nt = 0; nt < 2; ++nt) {
                    f16x8 vf = *reinterpret_cast<const f16x8*>(
                        &Vb[(nt * 32 + l31) * LDV + kt * 32 + cl * 16 + grp * 8]);
                    Oacc[0][nt] = __builtin_amdgcn_mfma_f32_32x32x16_f16(pfrag[0][cl], vf, Oacc[0][nt], 0, 0, 0);
                    Oacc[1][nt] = __builtin_amdgcn_mfma_f32_32x32x16_f16(pfrag[1][cl], vf, Oacc[1][nt], 0, 0, 0);
                }
            }
            __builtin_amdgcn_s_setprio(0);
        }

        BAR_LGKM();
    }

    // l partials
    lsum[0] += __shfl_xor(lsum[0], 32);
    lsum[1] += __shfl_xor(lsum[1], 32);
    if (grp == 0) {
        lpart[(size_t)bh * kT + q0 + qw + l31]      = lsum[0];
        lpart[(size_t)bh * kT + q0 + qw + 32 + l31] = lsum[1];
    }

    // unnormalized partial O (fp16)
    #pragma unroll
    for (int qg = 0; qg < 2; ++qg)
        #pragma unroll
        for (int g = 0; g < 4; ++g)
            #pragma unroll
            for (int r = 0; r < 4; ++r) {
                const int reg = g * 4 + r;
                const int ql  = r + 8 * g + 4 * grp;
                const size_t orow = (size_t)(b * kT + q0 + qw + qg * 32 + ql);
                #pragma unroll
                for (int nt = 0; nt < 2; ++nt)
                    Opart[orow * kD + h * 64 + nt * 32 + l31] = (_Float16)Oacc[qg][nt][reg];
            }
}

// ---------------------------------------------------------------------------
extern "C" void kernel_launch(void* const* d_in, const int* in_sizes, int n_in,
                              void* d_out, int out_size, void* d_ws, size_t ws_size,
                              hipStream_t stream) {
    const float* x  = (const float*)d_in[0];
    const float* Wq = (const float*)d_in[1];
    const float* bq = (const float*)d_in[2];
    const float* Wk = (const float*)d_in[3];
    const float* bk = (const float*)d_in[4];
    const float* Wv = (const float*)d_in[5];
    const float* bv = (const float*)d_in[6];
    const float* Wo = (const float*)d_in[7];
    const float* bo = (const float*)d_in[8];
    float* out = (float*)d_out;

    char* ws = (char*)d_ws;
    _Float16* Xh    = (_Float16*)(ws);                         // 16 MB (-> Op0)
    _Float16* Wqkvh = (_Float16*)(ws + 16777216);              // 6 MB (-> lp[2])
    _Float16* Woh   = (_Float16*)(ws + 23068672);              // 2 MB
    float*    bqkv  = (float*)   (ws + 25165824);              // 16 KB
    _Float16* QKVh  = (_Float16*)(ws + 25182208);              // 48 MB
    _Float16* Vtb   = (_Float16*)(ws + 75513856);              // 16 MB
    _Float16* Ohb   = (_Float16*)(ws + 92291072);              // 16 MB (-> Op1)

    _Float16* Op0 = Xh;                        // dead after QKV GEMM
    _Float16* Op1 = Ohb;
    float*    lp  = (float*)(ws + 16777216);   // 2 x 512 KB in dead Wqkvh

    // casts + bias concat
    cast_all<<<12291, 256, 0, stream>>>(x, Wq, Wk, Wv, Wo, bq, bk, bv,
                                        Xh, Wqkvh, Woh, bqkv);

    // fused QKV projection with RoPE epilogue + direct slot-permuted V->Vt
    gemm_qkv<<<dim3(kBT / 128, kQKVN / 128), 256, 0, stream>>>(
        Xh, Wqkvh, bqkv, QKVh, Vtb, kBT, kQKVN, kD);

    // split-K flash attention (S=2), 2-phase double-buffered, raw barriers
    attn_mfma<<<1024, 256, 0, stream>>>(QKVh, Vtb, Op0, Op1, lp);

    // output projection with fused split-merge + normalization (fp32 out)
    gemm_out_fused<<<dim3(kBT / 128, kD / 128), 256, 0, stream>>>(
        Op0, Op1, lp, Woh, bo, out);
}

// Round 6
// 297.128 us; speedup vs baseline: 1.0318x; 1.0277x over previous
//
#include <hip/hip_runtime.h>
#include <cstddef>
#include <cstdint>

// Problem constants
constexpr int kB   = 4;
constexpr int kT   = 2048;
constexpr int kD   = 1024;   // d_model
constexpr int kH   = 16;     // heads
constexpr int kDh  = 64;     // head dim
constexpr int kBT  = kB * kT;          // 8192 rows
constexpr int kQKVN = 3 * kD;          // 3072

typedef _Float16 f16x8 __attribute__((ext_vector_type(8)));
typedef _Float16 f16x4 __attribute__((ext_vector_type(4)));
typedef _Float16 f16x2 __attribute__((ext_vector_type(2)));
typedef float    f32x4  __attribute__((ext_vector_type(4)));
typedef float    f32x16 __attribute__((ext_vector_type(16)));

#define GLD16(g, l)                                                        \
    __builtin_amdgcn_global_load_lds(                                      \
        (const __attribute__((address_space(1))) void*)(g),                \
        (__attribute__((address_space(3))) void*)(l), 16, 0, 0)

// raw barrier: drain LDS ops only, leave global prefetch loads in flight
#define BAR_LGKM() do {                                                    \
    asm volatile("s_waitcnt lgkmcnt(0)" ::: "memory");                     \
    __builtin_amdgcn_s_barrier();                                          \
} while (0)

static __device__ __forceinline__ int pkrtz_i(float a, float b) {
    auto t = __builtin_amdgcn_cvt_pkrtz(a, b);   // v_cvt_pkrtz_f16_f32
    return *reinterpret_cast<int*>(&t);
}

// ---------------------------------------------------------------------------
// all fp32->fp16 casts + bias concat in one dispatch
// ---------------------------------------------------------------------------
__global__ __launch_bounds__(256) void cast_all(const float* __restrict__ x,
                                                const float* __restrict__ Wq,
                                                const float* __restrict__ Wk,
                                                const float* __restrict__ Wv,
                                                const float* __restrict__ Wo,
                                                const float* __restrict__ bq,
                                                const float* __restrict__ bk,
                                                const float* __restrict__ bv,
                                                _Float16* __restrict__ Xh,
                                                _Float16* __restrict__ Wqkvh,
                                                _Float16* __restrict__ Woh,
                                                float* __restrict__ bqkv) {
    const int i = blockIdx.x * 256 + threadIdx.x;
    if (i >= 3145728) {                 // bias concat: 768 float4 groups
        const int j = i - 3145728;
        if (j < 768) {
            const float* bs = (j < 256) ? bq : (j < 512 ? bk : bv);
            const int jo = j & 255;
            reinterpret_cast<float4*>(bqkv)[j] =
                reinterpret_cast<const float4*>(bs)[jo];
        }
        return;
    }
    const float* src; _Float16* dst; int off;
    if (i < 2097152)      { src = x;  dst = Xh;              off = i; }
    else if (i < 2359296) { src = Wq; dst = Wqkvh;           off = i - 2097152; }
    else if (i < 2621440) { src = Wk; dst = Wqkvh + 1048576; off = i - 2359296; }
    else if (i < 2883584) { src = Wv; dst = Wqkvh + 2097152; off = i - 2621440; }
    else                  { src = Wo; dst = Woh;             off = i - 2883584; }
    const float4 v = reinterpret_cast<const float4*>(src)[off];
    f16x4 o = { (_Float16)v.x, (_Float16)v.y, (_Float16)v.z, (_Float16)v.w };
    reinterpret_cast<f16x4*>(dst)[off] = o;
}

// ---------------------------------------------------------------------------
// fp16 MFMA GEMM (QKV projection): C[M,N] = A[M,K] @ B[N,K]^T + bias
// BK=64 staged as two 32-K chunks in separate LDS regions (GLD16-compatible).
// 2D grid (default dispatch order — R9's 1D swizzle regressed A-locality).
// RoPE fused in the epilogue for cols<2048 (pair partner is lane^1); Q half
// pre-scaled by log2(e)/8 for the max-free exp2 softmax.
// (R2 structure — R3's chunked 2-phase and R4's V-fusion both regressed.)
// ---------------------------------------------------------------------------
__global__ __launch_bounds__(256) void gemm_qkv(const _Float16* __restrict__ A,
                                                const _Float16* __restrict__ B,
                                                const float* __restrict__ bias,
                                                _Float16* __restrict__ C,
                                                int M, int N, int K) {
    constexpr int BK = 64;
    __shared__ _Float16 As[128 * BK];   // [ko][128][32] chunked
    __shared__ _Float16 Bs[128 * BK];

    const int tid  = threadIdx.x;
    const int wave = tid >> 6;
    const int lane = tid & 63;
    const int quad = lane >> 4;
    const int r16  = lane & 15;
    const int m0 = blockIdx.x * 128;
    const int n0 = blockIdx.y * 128;

    const int srow = lane >> 2;
    const int scol = (lane & 3) * 8;
    const _Float16* Ag0 = A + (size_t)(m0 + wave * 16 + srow) * K + scol;
    const _Float16* Ag1 = A + (size_t)(m0 + 64 + wave * 16 + srow) * K + scol;
    const _Float16* Bg0 = B + (size_t)(n0 + wave * 16 + srow) * K + scol;
    const _Float16* Bg1 = B + (size_t)(n0 + 64 + wave * 16 + srow) * K + scol;
    _Float16* Al0 = &As[(size_t)wave * 512];
    _Float16* Al1 = &As[(size_t)(wave + 4) * 512];
    _Float16* Bl0 = &Bs[(size_t)wave * 512];
    _Float16* Bl1 = &Bs[(size_t)(wave + 4) * 512];

    const int wm = (wave & 1) * 64;
    const int wn = (wave >> 1) * 64;

    f32x4 acc[4][4] = {};

    for (int k0 = 0; k0 < K; k0 += BK) {
        GLD16(Ag0 + k0,      Al0);
        GLD16(Ag1 + k0,      Al1);
        GLD16(Ag0 + k0 + 32, Al0 + 4096);
        GLD16(Ag1 + k0 + 32, Al1 + 4096);
        GLD16(Bg0 + k0,      Bl0);
        GLD16(Bg1 + k0,      Bl1);
        GLD16(Bg0 + k0 + 32, Bl0 + 4096);
        GLD16(Bg1 + k0 + 32, Bl1 + 4096);
        __syncthreads();

        #pragma unroll
        for (int ko = 0; ko < 2; ++ko) {
            f16x8 a[4], bf[4];
            #pragma unroll
            for (int mi = 0; mi < 4; ++mi)
                a[mi] = *reinterpret_cast<const f16x8*>(
                    &As[ko * 4096 + (wm + mi * 16 + r16) * 32 + quad * 8]);
            #pragma unroll
            for (int ni = 0; ni < 4; ++ni)
                bf[ni] = *reinterpret_cast<const f16x8*>(
                    &Bs[ko * 4096 + (wn + ni * 16 + r16) * 32 + quad * 8]);
            #pragma unroll
            for (int mi = 0; mi < 4; ++mi)
                #pragma unroll
                for (int ni = 0; ni < 4; ++ni)
                    acc[mi][ni] = __builtin_amdgcn_mfma_f32_16x16x32_f16(a[mi], bf[ni], acc[mi][ni], 0, 0, 0);
        }
        __syncthreads();
    }

    #pragma unroll
    for (int mi = 0; mi < 4; ++mi) {
        #pragma unroll
        for (int ni = 0; ni < 4; ++ni) {
            const int col = n0 + wn + ni * 16 + r16;
            const float bv = bias[col];
            #pragma unroll
            for (int r = 0; r < 4; ++r) {
                const int row = m0 + wm + mi * 16 + quad * 4 + r;
                float v = acc[mi][ni][r] + bv;
                // pair partner (col^1) lives in lane^1, same (mi,ni,r)
                const float vx = __shfl_xor(v, 1);
                if (col < 2048) {
                    const int t = row & (kT - 1);
                    const int p = (col & 63) >> 1;
                    const float rev = (float)t * ((float)p *
                        (1.0e-4f * 0.15915494309189535f));
                    const float s = __builtin_amdgcn_sinf(rev);
                    const float c = __builtin_amdgcn_cosf(rev);
                    const float sgn = (r16 & 1) ? s : -s;  // even: -s*partner
                    v = v * c + vx * sgn;
                    if (col < 1024) v *= 0.18033688011112443f;  // log2e/8
                }
                C[(size_t)row * N + col] = (_Float16)v;
            }
        }
    }
}

// ---------------------------------------------------------------------------
// Out projection with FUSED split-merge + normalization in the A-staging:
// A_norm[row][k] = (Op0[row][k] + Op1[row][k]) / (l0[row,h] + l1[row,h]),
// h = k>>6 (each thread's 32-col staging chunk lies within one head).
// B staged via GLD16 as usual. C written fp32.  (R2 structure, verified.)
// ---------------------------------------------------------------------------
__global__ __launch_bounds__(256) void gemm_out_fused(
        const _Float16* __restrict__ Op0,
        const _Float16* __restrict__ Op1,
        const float* __restrict__ lp,
        const _Float16* __restrict__ B,
        const float* __restrict__ bias,
        float* __restrict__ C) {
    constexpr int K = 1024, N = 1024, BK = 64;
    __shared__ _Float16 As[128 * BK];   // [ko][128][32] chunked
    __shared__ _Float16 Bs[128 * BK];

    const int tid  = threadIdx.x;
    const int wave = tid >> 6;
    const int lane = tid & 63;
    const int quad = lane >> 4;
    const int r16  = lane & 15;
    const int m0 = blockIdx.x * 128;
    const int n0 = blockIdx.y * 128;

    // B staging (GLD16)
    const int srow = lane >> 2;
    const int scol = (lane & 3) * 8;
    const _Float16* Bg0 = B + (size_t)(n0 + wave * 16 + srow) * K + scol;
    const _Float16* Bg1 = B + (size_t)(n0 + 64 + wave * 16 + srow) * K + scol;
    _Float16* Bl0 = &Bs[(size_t)wave * 512];
    _Float16* Bl1 = &Bs[(size_t)(wave + 4) * 512];

    // A fused staging: thread covers row m0+(tid>>1), 32 cols at (tid&1)*32
    const int arow = tid >> 1;
    const int ko_s = tid & 1;
    const int row  = m0 + arow;
    const int bb   = row >> 11, tt = row & 2047;
    const size_t abase = (size_t)row * K + ko_s * 32;
    constexpr size_t lstr = (size_t)kB * kH * kT;

    const int wm = (wave & 1) * 64;
    const int wn = (wave >> 1) * 64;

    f32x4 acc[4][4] = {};

    for (int k0 = 0; k0 < K; k0 += BK) {
        GLD16(Bg0 + k0,      Bl0);
        GLD16(Bg1 + k0,      Bl1);
        GLD16(Bg0 + k0 + 32, Bl0 + 4096);
        GLD16(Bg1 + k0 + 32, Bl1 + 4096);

        // A: load partials, merge + normalize, write LDS
        {
            const int h = k0 >> 6;   // iter-uniform head
            const size_t lidx = (size_t)(bb * 16 + h) * 2048 + tt;
            const float linv = 1.0f / (lp[lidx] + lp[lstr + lidx]);
            const _Float16 lh = (_Float16)linv;
            #pragma unroll
            for (int j = 0; j < 4; ++j) {
                f16x8 a0 = *reinterpret_cast<const f16x8*>(Op0 + abase + k0 + 8 * j);
                f16x8 a1 = *reinterpret_cast<const f16x8*>(Op1 + abase + k0 + 8 * j);
                f16x8 s = (a0 + a1) * lh;     // v_pk_add_f16 / v_pk_mul_f16
                *reinterpret_cast<f16x8*>(&As[ko_s * 4096 + arow * 32 + 8 * j]) = s;
            }
        }
        __syncthreads();

        #pragma unroll
        for (int ko = 0; ko < 2; ++ko) {
            f16x8 a[4], bf[4];
            #pragma unroll
            for (int mi = 0; mi < 4; ++mi)
                a[mi] = *reinterpret_cast<const f16x8*>(
                    &As[ko * 4096 + (wm + mi * 16 + r16) * 32 + quad * 8]);
            #pragma unroll
            for (int ni = 0; ni < 4; ++ni)
                bf[ni] = *reinterpret_cast<const f16x8*>(
                    &Bs[ko * 4096 + (wn + ni * 16 + r16) * 32 + quad * 8]);
            #pragma unroll
            for (int mi = 0; mi < 4; ++mi)
                #pragma unroll
                for (int ni = 0; ni < 4; ++ni)
                    acc[mi][ni] = __builtin_amdgcn_mfma_f32_16x16x32_f16(a[mi], bf[ni], acc[mi][ni], 0, 0, 0);
        }
        __syncthreads();
    }

    #pragma unroll
    for (int mi = 0; mi < 4; ++mi) {
        #pragma unroll
        for (int ni = 0; ni < 4; ++ni) {
            const int col = n0 + wn + ni * 16 + r16;
            const float bv = bias[col];
            #pragma unroll
            for (int r = 0; r < 4; ++r) {
                const int row2 = m0 + wm + mi * 16 + quad * 4 + r;
                C[(size_t)row2 * N + col] = acc[mi][ni][r] + bv;
            }
        }
    }
}

// ---------------------------------------------------------------------------
// V transpose: QKV[,2048+h*64+d] (rows t) -> Vt[bh][d][t'] with the key-slot
// PERMUTATION t' = swap(bit2,bit3 of t within each 16-key group).
// (Separate coalesced dispatch — R4's in-GEMM fusion scatter-stored and
// regressed; this version writes 16B/lane fully coalesced.)
// ---------------------------------------------------------------------------
__global__ __launch_bounds__(256) void transpose_v(const _Float16* __restrict__ QKV,
                                                   _Float16* __restrict__ Vt) {
    const int bh = blockIdx.y;
    const int t0 = blockIdx.x * 64;
    const int b = bh >> 4, h = bh & 15;
    __shared__ _Float16 T[64 * 72];

    const int tid = threadIdx.x;
    const int r   = tid >> 2;
    const int c0  = (tid & 3) * 16;
    const _Float16* src = QKV + (size_t)(b * kT + t0 + r) * kQKVN + 2048 + h * 64 + c0;
    *reinterpret_cast<f16x8*>(&T[r * 72 + c0])     = *reinterpret_cast<const f16x8*>(src);
    *reinterpret_cast<f16x8*>(&T[r * 72 + c0 + 8]) = *reinterpret_cast<const f16x8*>(src + 8);
    __syncthreads();

    const int d = tid >> 2, tc0 = (tid & 3) * 16;
    // slot s holds key sigma(s), sigma = swap bits 2<->3 (involution):
    // o0 (slots 0..7)  <- keys {0,1,2,3, 8,9,10,11}
    // o1 (slots 8..15) <- keys {4,5,6,7, 12,13,14,15}
    f16x8 o0, o1;
    #pragma unroll
    for (int j = 0; j < 4; ++j) o0[j]     = T[(tc0 + j)      * 72 + d];
    #pragma unroll
    for (int j = 0; j < 4; ++j) o0[4 + j] = T[(tc0 + 8 + j)  * 72 + d];
    #pragma unroll
    for (int j = 0; j < 4; ++j) o1[j]     = T[(tc0 + 4 + j)  * 72 + d];
    #pragma unroll
    for (int j = 0; j < 4; ++j) o1[4 + j] = T[(tc0 + 12 + j) * 72 + d];
    _Float16* dst = Vt + ((size_t)bh * 64 + d) * kT + t0 + tc0;
    *reinterpret_cast<f16x8*>(dst)     = o0;
    *reinterpret_cast<f16x8*>(dst + 8) = o1;
}

// ---------------------------------------------------------------------------
// Flash attention, split-K (S=2), XCD-locality swizzled 1D grid (1024 blocks):
//   id = qt*8 + (pair&7) + (pair>>3)*64, pair = bh*2+sp -> the 8 q-tile blocks
//   sharing one (bh,sp)'s 256 KB of K/V get IDs congruent mod 8 -> same XCD
//   -> K/V staging re-reads hit that XCD's L2 (R8/R9-verified, FETCH 164->49).
// T3 2-phase KVBLK=64 double-buffer, one barrier per tile, raw lgkm barriers;
// ds_writes to buf^1 at phase top, global prefetch loads stay in flight
// across barriers (R12-verified: 93.7 -> 91.8 us).
// R15: within-kt pipeline — issue BOTH qg's QK MFMA ladders back-to-back,
// THEN exp/pack both (qg1's MFMAs fill the pipe during qg0's S-wait; the
// exp/pack VALU runs while qg1's MFMAs drain). S[2] statically indexed.
// Max-free softmax => splits merge LINEARLY (O = sum O_s, l = sum l_s);
// merge happens inside gemm_out_fused.
// V slot-permuted in Vt -> PV A-frag is lane-local (no exchange).
// C/D layout: col = lane&31, row = (reg&3) + 8*(reg>>2) + 4*(lane>>5).
// A/B frag: row/col = lane&31, k = (lane>>5)*8 + j.  [HW-verified R3-R9]
// ---------------------------------------------------------------------------
__global__ __launch_bounds__(256) void attn_mfma(const _Float16* __restrict__ QKV,
                                                 const _Float16* __restrict__ Vt,
                                                 _Float16* __restrict__ Op0,
                                                 _Float16* __restrict__ Op1,
                                                 float* __restrict__ lp) {
    constexpr int LDK = 72, LDV = 72;
    __shared__ _Float16 Ks[2][64 * LDK];   // [buf][key 0..64)[d 0..64)
    __shared__ _Float16 Vts[2][64 * LDV];  // [buf][d 0..64)[slot 0..64)

    // swizzled decode
    const int id   = blockIdx.x;              // 0..1023
    const int qt   = (id >> 3) & 7;
    const int pair = ((id >> 6) << 3) + (id & 7);   // 0..127
    const int bh = pair >> 1;
    const int sp = pair & 1;
    const int b = bh >> 4, h = bh & 15;
    const int q0 = qt * 256;

    _Float16* __restrict__ Opart = sp ? Op1 : Op0;
    float* __restrict__ lpart = lp + (size_t)sp * (kB * kH * kT);

    const int tid  = threadIdx.x;
    const int wave = tid >> 6;
    const int lane = tid & 63;
    const int l31  = lane & 31;
    const int grp  = lane >> 5;
    const int qw   = wave * 64;

    // Q B-fragments from global (rope + log2e/8 scale already applied)
    f16x8 aq[2][4];
    #pragma unroll
    for (int qg = 0; qg < 2; ++qg) {
        const _Float16* qrow = QKV + (size_t)(b * kT + q0 + qw + qg * 32 + l31) * kQKVN + h * 64 + grp * 8;
        #pragma unroll
        for (int c = 0; c < 4; ++c)
            aq[qg][c] = *reinterpret_cast<const f16x8*>(qrow + c * 16);
    }

    f32x16 Oacc[2][2] = {};
    float lsum[2] = { 0.f, 0.f };

    // staging mapping: thread t covers row t>>2 (K: key; V: d), 16 f16 at (t&3)*16
    const int sr = tid >> 2;
    const int sc = (tid & 3) * 16;
    const int sofs = sr * LDK + sc;              // LDK == LDV
    const _Float16* kg = QKV + (size_t)(b * kT + sp * 1024 + sr) * kQKVN + 1024 + h * 64 + sc;
    const _Float16* vg = Vt + ((size_t)bh * 64 + sr) * (size_t)kT + sp * 1024 + sc;

    f16x8 kb0, kb1, vb0, vb1;

    // prologue: tile 0 -> regs -> buf0
    kb0 = *reinterpret_cast<const f16x8*>(kg);
    kb1 = *reinterpret_cast<const f16x8*>(kg + 8);
    vb0 = *reinterpret_cast<const f16x8*>(vg);
    vb1 = *reinterpret_cast<const f16x8*>(vg + 8);
    kg += (size_t)64 * kQKVN;  vg += 64;
    *reinterpret_cast<f16x8*>(&Ks[0][sofs])      = kb0;
    *reinterpret_cast<f16x8*>(&Ks[0][sofs + 8])  = kb1;
    *reinterpret_cast<f16x8*>(&Vts[0][sofs])     = vb0;
    *reinterpret_cast<f16x8*>(&Vts[0][sofs + 8]) = vb1;
    // tile 1 -> regs (loads stay in flight across the barrier)
    kb0 = *reinterpret_cast<const f16x8*>(kg);
    kb1 = *reinterpret_cast<const f16x8*>(kg + 8);
    vb0 = *reinterpret_cast<const f16x8*>(vg);
    vb1 = *reinterpret_cast<const f16x8*>(vg + 8);
    kg += (size_t)64 * kQKVN;  vg += 64;
    BAR_LGKM();

    #pragma unroll 1
    for (int it = 0; it < 16; ++it) {
        const int cur = it & 1;

        // phase top: write tile it+1 into buf^1 (overlaps compute on buf[cur])
        if (it < 15) {
            _Float16* kd = &Ks[cur ^ 1][sofs];
            _Float16* vd = &Vts[cur ^ 1][sofs];
            *reinterpret_cast<f16x8*>(kd)     = kb0;
            *reinterpret_cast<f16x8*>(kd + 8) = kb1;
            *reinterpret_cast<f16x8*>(vd)     = vb0;
            *reinterpret_cast<f16x8*>(vd + 8) = vb1;
        }
        // issue tile it+2's global loads (drained only by next phase's writes)
        if (it < 14) {
            kb0 = *reinterpret_cast<const f16x8*>(kg);
            kb1 = *reinterpret_cast<const f16x8*>(kg + 8);
            vb0 = *reinterpret_cast<const f16x8*>(vg);
            vb1 = *reinterpret_cast<const f16x8*>(vg + 8);
            kg += (size_t)64 * kQKVN;  vg += 64;
        }

        const _Float16* Kb = &Ks[cur][0];
        const _Float16* Vb = &Vts[cur][0];

        #pragma unroll
        for (int kt = 0; kt < 2; ++kt) {
            f16x8 kf[4];
            #pragma unroll
            for (int c = 0; c < 4; ++c)
                kf[c] = *reinterpret_cast<const f16x8*>(&Kb[(kt * 32 + l31) * LDK + c * 16 + grp * 8]);

            // --- both QK ladders first (back-to-back MFMA issue) ---
            f32x16 S[2];
            __builtin_amdgcn_s_setprio(1);
            #pragma unroll
            for (int qg = 0; qg < 2; ++qg) {
                S[qg] = {};
                #pragma unroll
                for (int c = 0; c < 4; ++c)
                    S[qg] = __builtin_amdgcn_mfma_f32_32x32x16_f16(kf[c], aq[qg][c], S[qg], 0, 0, 0);
            }
            __builtin_amdgcn_s_setprio(0);

            // --- exp/pack both (VALU overlaps qg1 MFMA drain) ---
            f16x8 pfrag[2][2];
            #pragma unroll
            for (int qg = 0; qg < 2; ++qg) {
                int q32[4][2];
                #pragma unroll
                for (int g = 0; g < 4; ++g) {
                    const float e0 = __builtin_amdgcn_exp2f(S[qg][g * 4 + 0]);
                    const float e1 = __builtin_amdgcn_exp2f(S[qg][g * 4 + 1]);
                    const float e2 = __builtin_amdgcn_exp2f(S[qg][g * 4 + 2]);
                    const float e3 = __builtin_amdgcn_exp2f(S[qg][g * 4 + 3]);
                    lsum[qg] += (e0 + e1) + (e2 + e3);
                    q32[g][0] = pkrtz_i(e0, e1);
                    q32[g][1] = pkrtz_i(e2, e3);
                }
                // V slot-permutation makes the PV A-frag lane-local:
                // pfrag[cl] = e[cl*8 + 0..7] packed, no exchange.
                #pragma unroll
                for (int cl = 0; cl < 2; ++cl) {
                    union { int u[4]; f16x8 v; } pu;
                    pu.u[0] = q32[2 * cl][0];
                    pu.u[1] = q32[2 * cl][1];
                    pu.u[2] = q32[2 * cl + 1][0];
                    pu.u[3] = q32[2 * cl + 1][1];
                    pfrag[qg][cl] = pu.v;
                }
            }

            __builtin_amdgcn_s_setprio(1);
            #pragma unroll
            for (int cl = 0; cl < 2; ++cl) {
                #pragma unroll
                for (int nt = 0; nt < 2; ++nt) {
                    f16x8 vf = *reinterpret_cast<const f16x8*>(
                        &Vb[(nt * 32 + l31) * LDV + kt * 32 + cl * 16 + grp * 8]);
                    Oacc[0][nt] = __builtin_amdgcn_mfma_f32_32x32x16_f16(pfrag[0][cl], vf, Oacc[0][nt], 0, 0, 0);
                    Oacc[1][nt] = __builtin_amdgcn_mfma_f32_32x32x16_f16(pfrag[1][cl], vf, Oacc[1][nt], 0, 0, 0);
                }
            }
            __builtin_amdgcn_s_setprio(0);
        }

        BAR_LGKM();
    }

    // l partials
    lsum[0] += __shfl_xor(lsum[0], 32);
    lsum[1] += __shfl_xor(lsum[1], 32);
    if (grp == 0) {
        lpart[(size_t)bh * kT + q0 + qw + l31]      = lsum[0];
        lpart[(size_t)bh * kT + q0 + qw + 32 + l31] = lsum[1];
    }

    // unnormalized partial O (fp16)
    #pragma unroll
    for (int qg = 0; qg < 2; ++qg)
        #pragma unroll
        for (int g = 0; g < 4; ++g)
            #pragma unroll
            for (int r = 0; r < 4; ++r) {
                const int reg = g * 4 + r;
                const int ql  = r + 8 * g + 4 * grp;
                const size_t orow = (size_t)(b * kT + q0 + qw + qg * 32 + ql);
                #pragma unroll
                for (int nt = 0; nt < 2; ++nt)
                    Opart[orow * kD + h * 64 + nt * 32 + l31] = (_Float16)Oacc[qg][nt][reg];
            }
}

// ---------------------------------------------------------------------------
extern "C" void kernel_launch(void* const* d_in, const int* in_sizes, int n_in,
                              void* d_out, int out_size, void* d_ws, size_t ws_size,
                              hipStream_t stream) {
    const float* x  = (const float*)d_in[0];
    const float* Wq = (const float*)d_in[1];
    const float* bq = (const float*)d_in[2];
    const float* Wk = (const float*)d_in[3];
    const float* bk = (const float*)d_in[4];
    const float* Wv = (const float*)d_in[5];
    const float* bv = (const float*)d_in[6];
    const float* Wo = (const float*)d_in[7];
    const float* bo = (const float*)d_in[8];
    float* out = (float*)d_out;

    char* ws = (char*)d_ws;
    _Float16* Xh    = (_Float16*)(ws);                         // 16 MB (-> Op0)
    _Float16* Wqkvh = (_Float16*)(ws + 16777216);              // 6 MB (-> lp[2])
    _Float16* Woh   = (_Float16*)(ws + 23068672);              // 2 MB
    float*    bqkv  = (float*)   (ws + 25165824);              // 16 KB
    _Float16* QKVh  = (_Float16*)(ws + 25182208);              // 48 MB
    _Float16* Vtb   = (_Float16*)(ws + 75513856);              // 16 MB
    _Float16* Ohb   = (_Float16*)(ws + 92291072);              // 16 MB (-> Op1)

    _Float16* Op0 = Xh;                        // dead after QKV GEMM
    _Float16* Op1 = Ohb;
    float*    lp  = (float*)(ws + 16777216);   // 2 x 512 KB in dead Wqkvh

    // casts + bias concat
    cast_all<<<12291, 256, 0, stream>>>(x, Wq, Wk, Wv, Wo, bq, bk, bv,
                                        Xh, Wqkvh, Woh, bqkv);

    // fused QKV projection with RoPE epilogue (2D grid)
    gemm_qkv<<<dim3(kBT / 128, kQKVN / 128), 256, 0, stream>>>(
        Xh, Wqkvh, bqkv, QKVh, kBT, kQKVN, kD);

    // V -> Vt[bh][d][t] (key-slot permuted)
    transpose_v<<<dim3(kT / 64, kB * kH), 256, 0, stream>>>(QKVh, Vtb);

    // split-K flash attention (S=2), 2-phase double-buffered, raw barriers
    attn_mfma<<<1024, 256, 0, stream>>>(QKVh, Vtb, Op0, Op1, lp);

    // output projection with fused split-merge + normalization (fp32 out)
    gemm_out_fused<<<dim3(kBT / 128, kD / 128), 256, 0, stream>>>(
        Op0, Op1, lp, Woh, bo, out);
}